// Round 11
// baseline (112.489 us; speedup 1.0000x reference)
//
#include <hip/hip_runtime.h>
#include <hip/hip_bf16.h>

// Problem constants
#define BB 8
#define HH 640
#define WW 640
#define HWN (HH * WW)          // 409600 pixels per batch
#define NUM_INST 16
#define NBLK 128               // blocks per batch -> 1024 total = exactly 4 blocks/CU
#define NBLK_TOT (NBLK * BB)
#define THREADS 256
#define NV 36                  // 16 s12 | 16 cnt | pos, all, or, posCnt
#define LN2F 0.69314718055994530942f

typedef float f32x2 __attribute__((ext_vector_type(2)));

// ws layout: ws[v * NBLK_TOT + g], g = b*NBLK + blockIdx.x. 36*1024*4 = 147456 B.
// Plain stores, no zero-init needed.

__device__ __forceinline__ void process_pixel(
    float p1, float p2, float c, float t, int k,
    f32x2* s12p, unsigned* cnt_pair, unsigned* cnt_odd,
    float& lgPos, float& lgAll, float& lgOr, unsigned& posCnt)
{
    float andp = p1 * p2;
    bool tpos = (t != 0.0f);
    bool cpos = (c != 0.0f);
    // BCE(and_preds, overlap): overlap exactly 0/1 -> one log2, select the argument.
    // Accumulate in log2 domain; multiply by ln2 once in the epilogue.
    // Clip at -100 never engages (inputs in [1e-4, 1-1e-4]).
    float argA = tpos ? andp : (1.0f - andp);
    float lg = __log2f(argA);
    lgAll += lg;
    lgPos = fmaf(c, lg, lgPos);        // c is exactly 0.0/1.0
    posCnt += (unsigned)__popcll(__ballot(cpos));   // scalar pipe
    // BCE(max(p1,p2), conf): conf exactly 0/1
    float mx = fmaxf(p1, p2);
    float argO = cpos ? mx : (1.0f - mx);
    lgOr += __log2f(argO);
    // instance term: |d1-d2| = |s1-s2|/cnt; e12 = d1^2-d2^2 = (a-b)(a+b-2)
    float ao = t * andp;               // t is exactly 0.0/1.0
    float a  = fmaxf(p1, ao);
    float b2 = fmaxf(p2, ao);
    float e12 = (a - b2) * ((a + b2) - 2.0f);
    // Pair-packed 16-bin histogram: 8 pair-compares, packed f32x2 adds.
    bool odd = (k & 1);
    unsigned long long hm = __ballot(odd);
    float e_lo = odd ? 0.0f : e12;
    float e_hi = odd ? e12 : 0.0f;
    int kp = k >> 1;
    #pragma unroll
    for (int j = 0; j < 8; ++j) {
        bool m = (kp == j);
        unsigned long long bm = __ballot(m);            // one v_cmp, shared
        f32x2 ad;
        ad.x = m ? e_lo : 0.0f;
        ad.y = m ? e_hi : 0.0f;
        s12p[j] += ad;                                  // v_pk_add_f32
        cnt_pair[j] += (unsigned)__popcll(bm);          // s_bcnt1 + s_add
        cnt_odd[j]  += (unsigned)__popcll(bm & hm);     // s_and + s_bcnt1 + s_add
    }
}

__global__ __launch_bounds__(THREADS) void overlap_main_kernel(
    const float* __restrict__ preds, const float* __restrict__ conf,
    const int* __restrict__ inst, const float* __restrict__ overlap,
    float* __restrict__ ws)
{
    const int b   = blockIdx.y;
    const int tid = threadIdx.x;

    const float4* p1v = (const float4*)(preds + (size_t)b * 2 * HWN);
    const float4* p2v = (const float4*)(preds + (size_t)b * 2 * HWN + HWN);
    const float4* cv  = (const float4*)(conf    + (size_t)b * HWN);
    const float4* tv  = (const float4*)(overlap + (size_t)b * HWN);
    const int4*   kv  = (const int4*)(inst      + (size_t)b * HWN);

    f32x2 s12p[8];
    unsigned cnt_pair[8], cnt_odd[8];
    #pragma unroll
    for (int j = 0; j < 8; ++j) {
        s12p[j] = (f32x2){0.0f, 0.0f};
        cnt_pair[j] = 0u; cnt_odd[j] = 0u;
    }
    float lgPos = 0.0f, lgAll = 0.0f, lgOr = 0.0f;
    unsigned posCnt = 0u;

    // Grid-stride loop; trip count is block-uniform (blockIdx.x < 16 -> 4 iters,
    // else 3), so all 64 lanes are always active and ballots are exact.
    const int nvec   = HWN / 4;
    const int stride = NBLK * THREADS;
    for (int i = blockIdx.x * THREADS + tid; i < nvec; i += stride) {
        float4 A = p1v[i];
        float4 B = p2v[i];
        float4 C = cv[i];
        float4 T = tv[i];
        int4   K = kv[i];
        process_pixel(A.x, B.x, C.x, T.x, K.x, s12p, cnt_pair, cnt_odd, lgPos, lgAll, lgOr, posCnt);
        process_pixel(A.y, B.y, C.y, T.y, K.y, s12p, cnt_pair, cnt_odd, lgPos, lgAll, lgOr, posCnt);
        process_pixel(A.z, B.z, C.z, T.z, K.z, s12p, cnt_pair, cnt_odd, lgPos, lgAll, lgOr, posCnt);
        process_pixel(A.w, B.w, C.w, T.w, K.w, s12p, cnt_pair, cnt_odd, lgPos, lgAll, lgOr, posCnt);
    }

    // Butterfly-reduce the 19 per-lane floats (counts are wave-uniform SGPRs)
    float fv[19];
    #pragma unroll
    for (int j = 0; j < 8; ++j) {
        fv[2 * j]     = s12p[j].x;
        fv[2 * j + 1] = s12p[j].y;
    }
    fv[16] = lgPos; fv[17] = lgAll; fv[18] = lgOr;
    #pragma unroll
    for (int s = 32; s > 0; s >>= 1) {
        #pragma unroll
        for (int v = 0; v < 19; ++v) fv[v] += __shfl_xor(fv[v], s, 64);
    }

    __shared__ float wsum[4][NV];
    const int wave = tid >> 6;
    const int lane = tid & 63;
    if (lane == 0) {
        #pragma unroll
        for (int j = 0; j < 8; ++j) {
            wsum[wave][2 * j]          = fv[2 * j];
            wsum[wave][2 * j + 1]      = fv[2 * j + 1];
            wsum[wave][16 + 2 * j]     = (float)(cnt_pair[j] - cnt_odd[j]);
            wsum[wave][16 + 2 * j + 1] = (float)cnt_odd[j];
        }
        wsum[wave][32] = -LN2F * fv[16];   // posSum = -ln2 * sum(c*log2)
        wsum[wave][33] = -LN2F * fv[17];   // allSum = -ln2 * sum(log2)
        wsum[wave][34] = -LN2F * fv[18];   // orSum  = -ln2 * sum(log2)
        wsum[wave][35] = (float)posCnt;
    }
    __syncthreads();
    if (tid < NV) {
        float s = wsum[0][tid] + wsum[1][tid] + wsum[2][tid] + wsum[3][tid];
        int g = blockIdx.y * NBLK + blockIdx.x;
        ws[tid * NBLK_TOT + g] = s;   // plain store, no atomics
    }
}

__global__ __launch_bounds__(320) void overlap_finalize_kernel(
    const float* __restrict__ ws, float* __restrict__ out)
{
    __shared__ float seg[BB][NV];
    __shared__ float perkey[BB][NUM_INST];
    __shared__ float pres[BB][NUM_INST];
    __shared__ float binst[BB];
    const int t = threadIdx.x;   // 320 >= 8*36 = 288

    if (t < BB * NV) {
        int b = t / NV, v = t - (t / NV) * NV;
        const float4* p = (const float4*)(ws + v * NBLK_TOT + b * NBLK);
        float4 s4 = {0.0f, 0.0f, 0.0f, 0.0f};
        #pragma unroll 8
        for (int i = 0; i < NBLK / 4; ++i) {   // 32 independent float4 loads
            float4 q = p[i];
            s4.x += q.x; s4.y += q.y; s4.z += q.z; s4.w += q.w;
        }
        seg[b][v] = (s4.x + s4.y) + (s4.z + s4.w);
    }
    __syncthreads();

    if (t < BB * NUM_INST) {
        int b = t >> 4, k = t & 15;
        float c = seg[b][16 + k];
        bool present = c > 0.0f;
        float sc = present ? c : 1.0f;
        perkey[b][k] = present ? (1.0f - fabsf(seg[b][k]) / sc) : 0.0f;
        pres[b][k]   = present ? 1.0f : 0.0f;
    }
    __syncthreads();

    if (t < BB) {
        float s = 0.0f, nk = 0.0f;
        for (int k = 0; k < NUM_INST; ++k) { s += perkey[t][k]; nk += pres[t][k]; }
        binst[t] = s / nk;
    }
    __syncthreads();

    if (t == 0) {
        float instLoss = 0.0f, posS = 0.0f, allS = 0.0f, orS = 0.0f, posC = 0.0f;
        for (int b = 0; b < BB; ++b) {
            instLoss += binst[b];
            posS += seg[b][32];
            allS += seg[b][33];
            orS  += seg[b][34];
            posC += seg[b][35];
        }
        instLoss *= (1.0f / (float)BB);
        const float N = (float)BB * (float)HWN;
        float negS = allS - posS;
        float andLoss = posS / posC + negS / (N - posC);
        float orLoss  = orS / N;
        out[0] = 0.5f * andLoss + 0.25f * orLoss + 0.25f * instLoss;
    }
}

extern "C" void kernel_launch(void* const* d_in, const int* in_sizes, int n_in,
                              void* d_out, int out_size, void* d_ws, size_t ws_size,
                              hipStream_t stream) {
    const float* preds   = (const float*)d_in[0];
    const float* conf    = (const float*)d_in[1];
    const int*   inst    = (const int*)d_in[2];
    const float* overlap = (const float*)d_in[3];
    // d_in[4] (inds) is unused by the reference computation.
    float* ws  = (float*)d_ws;
    float* out = (float*)d_out;

    dim3 grid(NBLK, BB);
    overlap_main_kernel<<<grid, THREADS, 0, stream>>>(preds, conf, inst, overlap, ws);
    overlap_finalize_kernel<<<1, 320, 0, stream>>>(ws, out);
}

// Round 12
// 111.476 us; speedup vs baseline: 1.0091x; 1.0091x over previous
//
#include <hip/hip_runtime.h>
#include <hip/hip_bf16.h>

// Problem constants
#define BB 8
#define HH 640
#define WW 640
#define HWN (HH * WW)          // 409600 pixels per batch
#define NUM_INST 16
#define NBLK 128               // blocks per batch -> 1024 total = exactly 4 blocks/CU
#define NBLK_TOT (NBLK * BB)
#define THREADS 256
#define NV 36                  // 16 s12 | 16 cnt | pos, all, or, posCnt
#define LN2F 0.69314718055994530942f

// ws layout: ws[v * NBLK_TOT + g], g = b*NBLK + blockIdx.x. 36*1024*4 = 147456 B.
// Plain stores, no zero-init needed.

__device__ __forceinline__ void process_pixel(
    float p1, float p2, float c, float t, int k,
    float* s12, unsigned long long& h,
    float& lgPos, float& lgAll, float& lgOr, float& accCnt)
{
    float andp = p1 * p2;
    bool tpos = (t != 0.0f);
    bool cpos = (c != 0.0f);
    // BCE(and_preds, overlap): overlap exactly 0/1 -> one log2, select argument.
    // ln recovered by one *ln2 in the epilogue. Clip at -100 never engages
    // (inputs in [1e-4, 1-1e-4]).
    float argA = tpos ? andp : (1.0f - andp);
    float lg = __log2f(argA);
    lgAll += lg;
    lgPos = fmaf(c, lg, lgPos);        // c is exactly 0.0/1.0
    accCnt += c;                       // posCnt
    // BCE(max(p1,p2), conf): conf exactly 0/1
    float mx = fmaxf(p1, p2);
    float argO = cpos ? mx : (1.0f - mx);
    lgOr += __log2f(argO);
    // instance term: |d1-d2| = |s1-s2|/cnt; e12 = d1^2-d2^2 = (a-b)(a+b-2)
    float ao = t * andp;               // t is exactly 0.0/1.0
    float a  = fmaxf(p1, ao);
    float b2 = fmaxf(p2, ao);
    float e12 = (a - b2) * ((a + b2) - 2.0f);
    // Count histogram: ONE packed-nibble u64 update (no ballots, no SALU hazard,
    // no 16 cndmask+adds). Nibble k counts pixels with inst==k; <=8 per u64.
    h += 1ull << (k << 2);
    // Value histogram: 16 x (shared v_cmp + cndmask + add)
    #pragma unroll
    for (int j = 0; j < NUM_INST; ++j) {
        bool m = (k == j);
        s12[j] += m ? e12 : 0.0f;
    }
}

__device__ __forceinline__ void process_vec4(
    int i,
    const float4* __restrict__ p1v, const float4* __restrict__ p2v,
    const float4* __restrict__ cv,  const float4* __restrict__ tv,
    const int4*   __restrict__ kv,
    float* s12, unsigned long long& h,
    float& lgPos, float& lgAll, float& lgOr, float& accCnt)
{
    float4 A = p1v[i];
    float4 B = p2v[i];
    float4 C = cv[i];
    float4 T = tv[i];
    int4   K = kv[i];
    process_pixel(A.x, B.x, C.x, T.x, K.x, s12, h, lgPos, lgAll, lgOr, accCnt);
    process_pixel(A.y, B.y, C.y, T.y, K.y, s12, h, lgPos, lgAll, lgOr, accCnt);
    process_pixel(A.z, B.z, C.z, T.z, K.z, s12, h, lgPos, lgAll, lgOr, accCnt);
    process_pixel(A.w, B.w, C.w, T.w, K.w, s12, h, lgPos, lgAll, lgOr, accCnt);
}

__global__ __launch_bounds__(THREADS) void overlap_main_kernel(
    const float* __restrict__ preds, const float* __restrict__ conf,
    const int* __restrict__ inst, const float* __restrict__ overlap,
    float* __restrict__ ws)
{
    const int b   = blockIdx.y;
    const int tid = threadIdx.x;

    const float4* p1v = (const float4*)(preds + (size_t)b * 2 * HWN);
    const float4* p2v = (const float4*)(preds + (size_t)b * 2 * HWN + HWN);
    const float4* cv  = (const float4*)(conf    + (size_t)b * HWN);
    const float4* tv  = (const float4*)(overlap + (size_t)b * HWN);
    const int4*   kv  = (const int4*)(inst      + (size_t)b * HWN);

    float s12[NUM_INST];
    #pragma unroll
    for (int j = 0; j < NUM_INST; ++j) s12[j] = 0.0f;
    unsigned long long h0 = 0ull, h1 = 0ull;   // nibble-packed counts, <=8 each
    float lgPos = 0.0f, lgAll = 0.0f, lgOr = 0.0f, accCnt = 0.0f;

    // 3 or 4 iterations, block-uniform (blockIdx.x < 16 -> 4), all lanes active.
    const int nvec   = HWN / 4;
    const int stride = NBLK * THREADS;
    int i = blockIdx.x * THREADS + tid;
    process_vec4(i, p1v, p2v, cv, tv, kv, s12, h0, lgPos, lgAll, lgOr, accCnt); i += stride;
    process_vec4(i, p1v, p2v, cv, tv, kv, s12, h0, lgPos, lgAll, lgOr, accCnt); i += stride;
    process_vec4(i, p1v, p2v, cv, tv, kv, s12, h1, lgPos, lgAll, lgOr, accCnt); i += stride;
    if (i < nvec)
        process_vec4(i, p1v, p2v, cv, tv, kv, s12, h1, lgPos, lgAll, lgOr, accCnt);

    // Expand nibbles -> u16 fields as 8 u32s (carry-free: fields never overflow;
    // per-wave max per field = 64 lanes * 16 = 1024 < 65536).
    unsigned ev[8];
    #pragma unroll
    for (int q = 0; q < 4; ++q) {
        unsigned long long e = ((h0 >> (4 * q)) & 0x000F000F000F000FULL)
                             + ((h1 >> (4 * q)) & 0x000F000F000F000FULL);
        ev[2 * q]     = (unsigned)e;
        ev[2 * q + 1] = (unsigned)(e >> 32);
    }

    // Butterfly-reduce 20 floats + 8 packed-count u32s
    float fv[20];
    #pragma unroll
    for (int j = 0; j < NUM_INST; ++j) fv[j] = s12[j];
    fv[16] = lgPos; fv[17] = lgAll; fv[18] = lgOr; fv[19] = accCnt;
    #pragma unroll
    for (int s = 32; s > 0; s >>= 1) {
        #pragma unroll
        for (int v = 0; v < 20; ++v) fv[v] += __shfl_xor(fv[v], s, 64);
        #pragma unroll
        for (int e = 0; e < 8; ++e) ev[e] += (unsigned)__shfl_xor((int)ev[e], s, 64);
    }

    __shared__ float wsum[4][NV];
    const int wave = tid >> 6;
    const int lane = tid & 63;
    if (lane == 0) {
        #pragma unroll
        for (int j = 0; j < NUM_INST; ++j) wsum[wave][j] = fv[j];
        #pragma unroll
        for (int k = 0; k < NUM_INST; ++k) {
            int q = k & 3, f = k >> 2;
            unsigned w = ev[2 * q + (f >> 1)];
            unsigned cnt = (w >> (16 * (f & 1))) & 0xFFFFu;
            wsum[wave][16 + k] = (float)cnt;
        }
        wsum[wave][32] = -LN2F * fv[16];   // posSum = -ln2 * sum(c*log2)
        wsum[wave][33] = -LN2F * fv[17];   // allSum = -ln2 * sum(log2)
        wsum[wave][34] = -LN2F * fv[18];   // orSum  = -ln2 * sum(log2)
        wsum[wave][35] = fv[19];           // posCnt
    }
    __syncthreads();
    if (tid < NV) {
        float s = wsum[0][tid] + wsum[1][tid] + wsum[2][tid] + wsum[3][tid];
        int g = blockIdx.y * NBLK + blockIdx.x;
        ws[tid * NBLK_TOT + g] = s;   // plain store, no atomics
    }
}

__global__ __launch_bounds__(320) void overlap_finalize_kernel(
    const float* __restrict__ ws, float* __restrict__ out)
{
    __shared__ float seg[BB][NV];
    __shared__ float perkey[BB][NUM_INST];
    __shared__ float pres[BB][NUM_INST];
    __shared__ float binst[BB];
    const int t = threadIdx.x;   // 320 >= 8*36 = 288

    if (t < BB * NV) {
        int b = t / NV, v = t - (t / NV) * NV;
        const float4* p = (const float4*)(ws + v * NBLK_TOT + b * NBLK);
        float4 s4 = {0.0f, 0.0f, 0.0f, 0.0f};
        #pragma unroll 8
        for (int i = 0; i < NBLK / 4; ++i) {   // 32 independent float4 loads
            float4 q = p[i];
            s4.x += q.x; s4.y += q.y; s4.z += q.z; s4.w += q.w;
        }
        seg[b][v] = (s4.x + s4.y) + (s4.z + s4.w);
    }
    __syncthreads();

    if (t < BB * NUM_INST) {
        int b = t >> 4, k = t & 15;
        float c = seg[b][16 + k];
        bool present = c > 0.0f;
        float sc = present ? c : 1.0f;
        perkey[b][k] = present ? (1.0f - fabsf(seg[b][k]) / sc) : 0.0f;
        pres[b][k]   = present ? 1.0f : 0.0f;
    }
    __syncthreads();

    if (t < BB) {
        float s = 0.0f, nk = 0.0f;
        for (int k = 0; k < NUM_INST; ++k) { s += perkey[t][k]; nk += pres[t][k]; }
        binst[t] = s / nk;
    }
    __syncthreads();

    if (t == 0) {
        float instLoss = 0.0f, posS = 0.0f, allS = 0.0f, orS = 0.0f, posC = 0.0f;
        for (int b = 0; b < BB; ++b) {
            instLoss += binst[b];
            posS += seg[b][32];
            allS += seg[b][33];
            orS  += seg[b][34];
            posC += seg[b][35];
        }
        instLoss *= (1.0f / (float)BB);
        const float N = (float)BB * (float)HWN;
        float negS = allS - posS;
        float andLoss = posS / posC + negS / (N - posC);
        float orLoss  = orS / N;
        out[0] = 0.5f * andLoss + 0.25f * orLoss + 0.25f * instLoss;
    }
}

extern "C" void kernel_launch(void* const* d_in, const int* in_sizes, int n_in,
                              void* d_out, int out_size, void* d_ws, size_t ws_size,
                              hipStream_t stream) {
    const float* preds   = (const float*)d_in[0];
    const float* conf    = (const float*)d_in[1];
    const int*   inst    = (const int*)d_in[2];
    const float* overlap = (const float*)d_in[3];
    // d_in[4] (inds) is unused by the reference computation.
    float* ws  = (float*)d_ws;
    float* out = (float*)d_out;

    dim3 grid(NBLK, BB);
    overlap_main_kernel<<<grid, THREADS, 0, stream>>>(preds, conf, inst, overlap, ws);
    overlap_finalize_kernel<<<1, 320, 0, stream>>>(ws, out);
}